// Round 3
// baseline (260.111 us; speedup 1.0000x reference)
//
#include <hip/hip_runtime.h>
#include <math.h>

typedef float vf4 __attribute__((ext_vector_type(4)));

// Bitonic network layer tables: l = blk*(blk+1)/2 + lay, m = 2^(blk-lay)
static constexpr int LLB[36] = {
  0,
  1,0,
  2,1,0,
  3,2,1,0,
  4,3,2,1,0,
  5,4,3,2,1,0,
  6,5,4,3,2,1,0,
  7,6,5,4,3,2,1,0
};
static constexpr int LBLK[36] = {
  0,
  1,1,
  2,2,2,
  3,3,3,3,
  4,4,4,4,4,
  5,5,5,5,5,5,
  6,6,6,6,6,6,6,
  7,7,7,7,7,7,7,7
};

// ---------------------------------------------------------------------------
// Kernel A: coefficient generation.
// u[b][l][k] = d ? 1-alpha : alpha,  alpha = atan(10*(v[q]-v[p]))/pi + 0.5
// Both pair outputs use the SAME u:
//   new[p] = u*x[p] + (1-u)*x[q];  new[q] = u*x[q] + (1-u)*x[p]
// ---------------------------------------------------------------------------
__global__ __launch_bounds__(128) void k_ugen(const float* __restrict__ vec,
                                              float* __restrict__ U) {
  const int b = blockIdx.x;
  const int k = threadIdx.x;            // 0..127 = pair index
  const float* v = vec + b * 256;
  float* ub = U + (size_t)b * 4608;
  #pragma unroll
  for (int l = 0; l < 36; ++l) {
    const int lb  = LLB[l];
    const int blk = LBLK[l];
    const int m = 1 << lb;
    const int p = ((k >> lb) << (lb + 1)) | (k & (m - 1));
    const int q = p + m;
    const int d = (p >> (blk + 1)) & 1;
    const float alpha =
        atanf(10.0f * (v[q] - v[p])) * 0.3183098861837907f + 0.5f;
    ub[l * 128 + k] = d ? (1.0f - alpha) : alpha;
  }
}

// ---------------------------------------------------------------------------
// Fused kernel: all 36 layers.  Block = (b, rowgroup g of 64 rows), 256 thr.
// Thread = (chunk c of 64 cols, row rr), tid = c*64 + rr.
//
// Phase 1 (layers 0..20, m<=32): row e_i stays inside its aligned 64-col
// group, so each thread recomputes the in-register butterfly for ITS OWN row
// (waves duplicate each other's phase-1 work — ~2.7K cycles — which deletes
// the 67 MB staged global round-trip + a kernel launch).
//
// Phase 2/3 (layers 21..35): l=21 consumes the phase-1 registers directly;
// two LDS exchanges (m=128, m=64) lane-contiguous; final XOR-swizzled LDS
// transpose so global stores are 1KB lane-contiguous per wave.
// ---------------------------------------------------------------------------
__global__ __launch_bounds__(256) void k_main(const float* __restrict__ U,
                                              float* __restrict__ out) {
  const int bg = blockIdx.x;
  const int b = bg >> 2;
  const int g = bg & 3;
  const int c  = threadIdx.x >> 6;      // chunk 0..3 (== wave id)
  const int rr = threadIdx.x & 63;      // row within group
  __shared__ float4 ex4[4096];          // 64 KB, multi-purpose
  float y[64];

  const int ub = __builtin_amdgcn_readfirstlane(b * 4608);

  // ---- phase 1: layers 0..20 on row (64g + rr), in registers
  {
    float r[64];
    #pragma unroll
    for (int j = 0; j < 64; ++j) r[j] = (j == rr) ? 1.0f : 0.0f;

    const int ubase = __builtin_amdgcn_readfirstlane(b * 4608 + 32 * g);
    #pragma unroll
    for (int l = 0; l < 21; ++l) {
      const int lb = LLB[l];
      const int m = 1 << lb;
      const float* ul = U + ubase + l * 128;
      #pragma unroll
      for (int kl = 0; kl < 32; ++kl) {
        const int p = ((kl >> lb) << (lb + 1)) | (kl & (m - 1));
        const int q = p + m;
        const float u = ul[kl];
        const float t  = r[p] - r[q];
        const float np = fmaf(u, t, r[q]);    // u*p + (1-u)*q
        const float nq = fmaf(-u, t, r[p]);   // u*q + (1-u)*p
        r[p] = np;
        r[q] = nq;
      }
    }

    // ---- l=21: blk6, m=64.  Support of row (64g+rr) = cols [64g,64g+64);
    // exactly one chunk of each pair is nonzero: y = r * (u or 1-u), or 0.
    const int ap = g >> 1;              // 128-region
    if ((c >> 1) == ap) {
      const float* u21 = U + ub + 21 * 128 + 64 * ap;
      const bool sm = ((c & 1) == (g & 1));   // my side == nonzero side
      #pragma unroll
      for (int t = 0; t < 16; ++t) {
        const float u0 = u21[4*t+0], u1 = u21[4*t+1];
        const float u2 = u21[4*t+2], u3 = u21[4*t+3];
        y[4*t+0] = r[4*t+0] * (sm ? u0 : 1.0f - u0);
        y[4*t+1] = r[4*t+1] * (sm ? u1 : 1.0f - u1);
        y[4*t+2] = r[4*t+2] * (sm ? u2 : 1.0f - u2);
        y[4*t+3] = r[4*t+3] * (sm ? u3 : 1.0f - u3);
      }
    } else {
      #pragma unroll
      for (int j = 0; j < 64; ++j) y[j] = 0.0f;
    }
  }

  const int cb = __builtin_amdgcn_readfirstlane(32 * c);

  // ---- blk6 in-register layers l=22..27 (m=32..1), pairs k in [32c,32c+32)
  #pragma unroll
  for (int l = 22; l < 28; ++l) {
    const int lb = LLB[l];
    const int m = 1 << lb;
    const float* ul = U + ub + l * 128 + cb;
    #pragma unroll
    for (int kl = 0; kl < 32; ++kl) {
      const int p = ((kl >> lb) << (lb + 1)) | (kl & (m - 1));
      const int q = p + m;
      const float u = ul[kl];
      const float t  = y[p] - y[q];
      const float np = fmaf(u, t, y[q]);
      const float nq = fmaf(-u, t, y[p]);
      y[p] = np;
      y[q] = nq;
    }
  }

  // ---- exchange 1 + l=28 (blk7, m=128): partner chunk c^2
  #pragma unroll
  for (int t = 0; t < 16; ++t)
    ex4[(c * 16 + t) * 64 + rr] =
        make_float4(y[4*t], y[4*t+1], y[4*t+2], y[4*t+3]);
  __syncthreads();
  {
    const int pc = c ^ 2;
    const float* u28 = U + ub + 28 * 128 + 64 * (c & 1);
    #pragma unroll
    for (int t = 0; t < 16; ++t) {
      const float4 p4 = ex4[(pc * 16 + t) * 64 + rr];
      const float u0 = u28[4*t+0], u1 = u28[4*t+1];
      const float u2 = u28[4*t+2], u3 = u28[4*t+3];
      y[4*t+0] = fmaf(u0, y[4*t+0] - p4.x, p4.x);
      y[4*t+1] = fmaf(u1, y[4*t+1] - p4.y, p4.y);
      y[4*t+2] = fmaf(u2, y[4*t+2] - p4.z, p4.z);
      y[4*t+3] = fmaf(u3, y[4*t+3] - p4.w, p4.w);
    }
  }
  __syncthreads();

  // ---- exchange 2 + l=29 (blk7, m=64): partner chunk c^1
  #pragma unroll
  for (int t = 0; t < 16; ++t)
    ex4[(c * 16 + t) * 64 + rr] =
        make_float4(y[4*t], y[4*t+1], y[4*t+2], y[4*t+3]);
  __syncthreads();
  {
    const int pc = c ^ 1;
    const float* u29 = U + ub + 29 * 128 + 64 * (c >> 1);
    #pragma unroll
    for (int t = 0; t < 16; ++t) {
      const float4 p4 = ex4[(pc * 16 + t) * 64 + rr];
      const float u0 = u29[4*t+0], u1 = u29[4*t+1];
      const float u2 = u29[4*t+2], u3 = u29[4*t+3];
      y[4*t+0] = fmaf(u0, y[4*t+0] - p4.x, p4.x);
      y[4*t+1] = fmaf(u1, y[4*t+1] - p4.y, p4.y);
      y[4*t+2] = fmaf(u2, y[4*t+2] - p4.z, p4.z);
      y[4*t+3] = fmaf(u3, y[4*t+3] - p4.w, p4.w);
    }
  }

  // ---- blk7 in-register layers l=30..35 (m=32..1)
  #pragma unroll
  for (int l = 30; l < 36; ++l) {
    const int lb = LLB[l];
    const int m = 1 << lb;
    const float* ul = U + ub + l * 128 + cb;
    #pragma unroll
    for (int kl = 0; kl < 32; ++kl) {
      const int p = ((kl >> lb) << (lb + 1)) | (kl & (m - 1));
      const int q = p + m;
      const float u = ul[kl];
      const float t  = y[p] - y[q];
      const float np = fmaf(u, t, y[q]);
      const float nq = fmaf(-u, t, y[p]);
      y[p] = np;
      y[q] = nq;
    }
  }

  // ---- XOR-swizzled LDS transpose -> coalesced 1KB/wave stores.
  // Block's output region is contiguous 64KB: rows [g*64, g*64+64) of batch b.
  __syncthreads();   // exchange-2 reads must finish before ex4 is overwritten
  #pragma unroll
  for (int t = 0; t < 16; ++t) {
    const int q = c * 16 + t;
    ex4[rr * 64 + (q ^ (rr & 7))] =
        make_float4(y[4*t], y[4*t+1], y[4*t+2], y[4*t+3]);
  }
  __syncthreads();
  {
    float4* out4 = (float4*)out + ((size_t)(b * 256 + g * 64)) * 64;
    const int tid = threadIdx.x;
    #pragma unroll
    for (int it = 0; it < 16; ++it) {
      const int fq = it * 256 + tid;     // float4 index within the 64KB block
      const int r = fq >> 6;
      const int q = fq & 63;
      const float4 v4 = ex4[r * 64 + (q ^ (r & 7))];
      __builtin_nontemporal_store(*(const vf4*)&v4, (vf4*)&out4[fq]);
    }
  }
}

// ---------------------------------------------------------------------------
extern "C" void kernel_launch(void* const* d_in, const int* in_sizes, int n_in,
                              void* d_out, int out_size, void* d_ws, size_t ws_size,
                              hipStream_t stream) {
  const float* vec = (const float*)d_in[0];   // vectors (512,256) f32
  float* out = (float*)d_out;                 // (512,256,256) f32
  float* U = (float*)d_ws;                    // 512*36*128 f32 = 9.4 MB

  hipLaunchKernelGGL(k_ugen, dim3(512),  dim3(128), 0, stream, vec, U);
  hipLaunchKernelGGL(k_main, dim3(2048), dim3(256), 0, stream, U, out);
}

// Round 4
// 242.713 us; speedup vs baseline: 1.0717x; 1.0717x over previous
//
#include <hip/hip_runtime.h>
#include <math.h>

typedef float vf4 __attribute__((ext_vector_type(4)));

// Bitonic network layer tables: l = blk*(blk+1)/2 + lay, m = 2^(blk-lay)
static constexpr int LLB[36] = {
  0,
  1,0,
  2,1,0,
  3,2,1,0,
  4,3,2,1,0,
  5,4,3,2,1,0,
  6,5,4,3,2,1,0,
  7,6,5,4,3,2,1,0
};
static constexpr int LBLK[36] = {
  0,
  1,1,
  2,2,2,
  3,3,3,3,
  4,4,4,4,4,
  5,5,5,5,5,5,
  6,6,6,6,6,6,6,
  7,7,7,7,7,7,7,7
};

// ---------------------------------------------------------------------------
// Kernel A: coefficient generation.
// u[b][l][k] = d ? 1-alpha : alpha,  alpha = atan(10*(v[q]-v[p]))/pi + 0.5
// Both pair outputs use the SAME u:
//   new[p] = u*x[p] + (1-u)*x[q];  new[q] = u*x[q] + (1-u)*x[p]
//          = fma(u, me - other, other) on BOTH sides (side-symmetric).
// ---------------------------------------------------------------------------
__global__ __launch_bounds__(128) void k_ugen(const float* __restrict__ vec,
                                              float* __restrict__ U) {
  const int b = blockIdx.x;
  const int k = threadIdx.x;            // 0..127 = pair index
  const float* v = vec + b * 256;
  float* ub = U + (size_t)b * 4608;
  #pragma unroll
  for (int l = 0; l < 36; ++l) {
    const int lb  = LLB[l];
    const int blk = LBLK[l];
    const int m = 1 << lb;
    const int p = ((k >> lb) << (lb + 1)) | (k & (m - 1));
    const int q = p + m;
    const int d = (p >> (blk + 1)) & 1;
    const float alpha =
        atanf(10.0f * (v[q] - v[p])) * 0.3183098861837907f + 0.5f;
    ub[l * 128 + k] = d ? (1.0f - alpha) : alpha;
  }
}

// ---------------------------------------------------------------------------
// Fused kernel, occupancy-tuned: 32 KB LDS (half-round exchanges/transpose),
// VGPR<=128 via launch_bounds, wave-uniform skip of dead phase-1/blk6 work.
// Block = (b, rowgroup g of 64 rows), 256 thr; thread = (chunk c, row rr).
// ---------------------------------------------------------------------------
__global__ __launch_bounds__(256, 4) void k_main(const float* __restrict__ U,
                                                 float* __restrict__ out) {
  const int bg = blockIdx.x;
  const int b = bg >> 2;
  const int g = bg & 3;
  const int c  = threadIdx.x >> 6;      // chunk 0..3 (== wave id)
  const int rr = threadIdx.x & 63;      // row within group
  __shared__ float4 exh[2048];          // 32 KB half-buffer
  float y[64];

  const int ub = __builtin_amdgcn_readfirstlane(b * 4608);
  const int cb = __builtin_amdgcn_readfirstlane(32 * c);

  // After l=21 only chunks {g, g^1} are nonzero -> other waves skip to exch-1.
  const bool active = ((c >> 1) == (g >> 1));   // wave-uniform

  if (active) {
    // ---- phase 1: layers 0..20 on row (64g + rr), in registers
    float r[64];
    #pragma unroll
    for (int j = 0; j < 64; ++j) r[j] = (j == rr) ? 1.0f : 0.0f;

    const int ubase = __builtin_amdgcn_readfirstlane(b * 4608 + 32 * g);
    #pragma unroll
    for (int l = 0; l < 21; ++l) {
      const int lb = LLB[l];
      const int m = 1 << lb;
      const float* ul = U + ubase + l * 128;
      #pragma unroll
      for (int kl = 0; kl < 32; ++kl) {
        const int p = ((kl >> lb) << (lb + 1)) | (kl & (m - 1));
        const int q = p + m;
        const float u = ul[kl];
        const float t  = r[p] - r[q];
        const float np = fmaf(u, t, r[q]);    // u*p + (1-u)*q
        const float nq = fmaf(-u, t, r[p]);   // u*q + (1-u)*p
        r[p] = np;
        r[q] = nq;
      }
    }

    // ---- l=21 (m=64): one side of each pair is zero -> pure multiply.
    {
      const int ap = g >> 1;
      const float* u21 = U + ub + 21 * 128 + 64 * ap;
      const bool sm = ((c & 1) == (g & 1));
      #pragma unroll
      for (int j = 0; j < 64; ++j) {
        const float uj = u21[j];
        y[j] = r[j] * (sm ? uj : 1.0f - uj);
      }
    }

    // ---- blk6 in-register layers l=22..27 (m=32..1)
    #pragma unroll
    for (int l = 22; l < 28; ++l) {
      const int lb = LLB[l];
      const int m = 1 << lb;
      const float* ul = U + ub + l * 128 + cb;
      #pragma unroll
      for (int kl = 0; kl < 32; ++kl) {
        const int p = ((kl >> lb) << (lb + 1)) | (kl & (m - 1));
        const int q = p + m;
        const float u = ul[kl];
        const float t  = y[p] - y[q];
        const float np = fmaf(u, t, y[q]);
        const float nq = fmaf(-u, t, y[p]);
        y[p] = np;
        y[q] = nq;
      }
    }
  } else {
    #pragma unroll
    for (int j = 0; j < 64; ++j) y[j] = 0.0f;
  }

  // ---- exchange 1 (l=28, m=128, partner chunk c^2), two 32-elem halves
  {
    const int pc = c ^ 2;
    const float* u28 = U + ub + 28 * 128 + 64 * (c & 1);
    #pragma unroll
    for (int h = 0; h < 2; ++h) {
      const int e0 = 32 * h;
      #pragma unroll
      for (int t = 0; t < 8; ++t)
        exh[(c * 8 + t) * 64 + rr] = make_float4(
            y[e0+4*t], y[e0+4*t+1], y[e0+4*t+2], y[e0+4*t+3]);
      __syncthreads();
      #pragma unroll
      for (int t = 0; t < 8; ++t) {
        const float4 p4 = exh[(pc * 8 + t) * 64 + rr];
        y[e0+4*t+0] = fmaf(u28[e0+4*t+0], y[e0+4*t+0] - p4.x, p4.x);
        y[e0+4*t+1] = fmaf(u28[e0+4*t+1], y[e0+4*t+1] - p4.y, p4.y);
        y[e0+4*t+2] = fmaf(u28[e0+4*t+2], y[e0+4*t+2] - p4.z, p4.z);
        y[e0+4*t+3] = fmaf(u28[e0+4*t+3], y[e0+4*t+3] - p4.w, p4.w);
      }
      __syncthreads();
    }
  }

  // ---- exchange 2 (l=29, m=64, partner chunk c^1), two 32-elem halves
  {
    const int pc = c ^ 1;
    const float* u29 = U + ub + 29 * 128 + 64 * (c >> 1);
    #pragma unroll
    for (int h = 0; h < 2; ++h) {
      const int e0 = 32 * h;
      #pragma unroll
      for (int t = 0; t < 8; ++t)
        exh[(c * 8 + t) * 64 + rr] = make_float4(
            y[e0+4*t], y[e0+4*t+1], y[e0+4*t+2], y[e0+4*t+3]);
      __syncthreads();
      #pragma unroll
      for (int t = 0; t < 8; ++t) {
        const float4 p4 = exh[(pc * 8 + t) * 64 + rr];
        y[e0+4*t+0] = fmaf(u29[e0+4*t+0], y[e0+4*t+0] - p4.x, p4.x);
        y[e0+4*t+1] = fmaf(u29[e0+4*t+1], y[e0+4*t+1] - p4.y, p4.y);
        y[e0+4*t+2] = fmaf(u29[e0+4*t+2], y[e0+4*t+2] - p4.z, p4.z);
        y[e0+4*t+3] = fmaf(u29[e0+4*t+3], y[e0+4*t+3] - p4.w, p4.w);
      }
      __syncthreads();
    }
  }

  // ---- blk7 in-register layers l=30..35 (m=32..1)
  #pragma unroll
  for (int l = 30; l < 36; ++l) {
    const int lb = LLB[l];
    const int m = 1 << lb;
    const float* ul = U + ub + l * 128 + cb;
    #pragma unroll
    for (int kl = 0; kl < 32; ++kl) {
      const int p = ((kl >> lb) << (lb + 1)) | (kl & (m - 1));
      const int q = p + m;
      const float u = ul[kl];
      const float t  = y[p] - y[q];
      const float np = fmaf(u, t, y[q]);
      const float nq = fmaf(-u, t, y[p]);
      y[p] = np;
      y[q] = nq;
    }
  }

  // ---- XOR-swizzled LDS transpose -> coalesced 1KB/wave NT stores,
  // in two 32-row halves (32 KB each).  Out region = contiguous 64 KB.
  {
    float4* out4 = (float4*)out + ((size_t)(b * 256 + g * 64)) * 64;
    const int tid = threadIdx.x;
    #pragma unroll
    for (int h = 0; h < 2; ++h) {
      __syncthreads();   // prior reads of exh done
      if ((rr >> 5) == h) {
        const int r5 = rr & 31;
        #pragma unroll
        for (int t = 0; t < 16; ++t) {
          const int q = c * 16 + t;
          exh[r5 * 64 + (q ^ (rr & 7))] = make_float4(
              y[4*t], y[4*t+1], y[4*t+2], y[4*t+3]);
        }
      }
      __syncthreads();
      #pragma unroll
      for (int it = 0; it < 8; ++it) {
        const int fq = h * 2048 + it * 256 + tid; // float4 idx in 64KB block
        const int r = fq >> 6;
        const int q = fq & 63;
        const float4 v4 = exh[(r & 31) * 64 + (q ^ (r & 7))];
        __builtin_nontemporal_store(*(const vf4*)&v4, (vf4*)&out4[fq]);
      }
    }
  }
}

// ---------------------------------------------------------------------------
extern "C" void kernel_launch(void* const* d_in, const int* in_sizes, int n_in,
                              void* d_out, int out_size, void* d_ws, size_t ws_size,
                              hipStream_t stream) {
  const float* vec = (const float*)d_in[0];   // vectors (512,256) f32
  float* out = (float*)d_out;                 // (512,256,256) f32
  float* U = (float*)d_ws;                    // 512*36*128 f32 = 9.4 MB

  hipLaunchKernelGGL(k_ugen, dim3(512),  dim3(128), 0, stream, vec, U);
  hipLaunchKernelGGL(k_main, dim3(2048), dim3(256), 0, stream, U, out);
}